// Round 12
// baseline (102.665 us; speedup 1.0000x reference)
//
#include <hip/hip_runtime.h>
#include <hip/hip_bf16.h>
#include <cstdint>
#include <cstddef>

#define V      27578
#define NJ     24
#define KK     24000
#define NT2    1724          /* ceil(V/16) */
#define NCHUNK 25
#define VCHUNK 1104

// ---------------- k_pose LDS layout (f32/u32 word offsets) ----------------
#define LPD    0             // u32 [96 rows=(g*48+3v+c)][128] bf16-pair words, XOR-swizzled; kw 104..108 = shapedirs
#define LA     12288         // u32 [32 slots][116] lrot+beta bf16 pairs (k 0..206 lrot, 208..217 beta)
#define LRB    16000         // u32 [32][4 kgrp][16 n][4] res bf16 B-fragments
#define LVP    24192         // f32 [32 slots][68] vposed (vd*4+cd)
#define LT     26368         // f32 [32 slots][16 v][20] T matrices
#define LWA    36608         // u32 [2 g][4 kgrp][16 v][4] weights bf16 A-fragments
#define LTM2   37120         // f32 [96] template tile (g*48+n)
#define LROOT2 37216         // f32 [32 slots][3]
#define LPERM2 37312         // int [32]
#define LCNT2  37344         // int
#define LKB    37348         // int [2][8]
#define LDSW   37364         // 149,456 bytes

// ---------------- workspace layout (word offsets) ----------------
#define WS_JS   0            // f32 [2][24][33][25]  (k_js partials)
#define WS_LA   39600        // u32 [32][116]
#define WS_RB   43312        // u32 [32][256]
#define WS_ROOT 51824        // f32 [32][3]
#define WS_PERM 51920        // int [32]
#define WS_CNT  51952        // int
#define WS_KB   51956        // int [1725]  kb[i] = lower_bound(to_keep, 16*i)

typedef short short8 __attribute__((ext_vector_type(8)));
typedef float f32x4 __attribute__((ext_vector_type(4)));
typedef float f32x4a __attribute__((ext_vector_type(4), aligned(4)));   // dword-aligned vector load

union S8U4 { unsigned u[4]; uint4 u4; short8 s; };

__device__ __forceinline__ unsigned pk2(float a, float b) {
    __hip_bfloat162 h = __float22bfloat162_rn(float2{a, b});
    union { __hip_bfloat162 h; unsigned u; } cv; cv.h = h;
    return cv.u;
}

// LDS-only barrier: drains ds ops (lgkmcnt) but leaves the global prefetch
// (vmcnt) in flight — its wait moves to write_stage's data-flow use.
#define BAR_LGKM() do { \
    asm volatile("s_waitcnt lgkmcnt(0)\n\ts_barrier" ::: "memory"); \
    __builtin_amdgcn_sched_barrier(0); \
} while (0)

__constant__ int d_par[24] = {0,0,0,0,1,2,3,4,5,6,7,8,9,9,9,12,13,14,16,17,18,19,20,21};

// ---------------- Kernel A: JS/Jt partials over V-chunks ----------------
__global__ __launch_bounds__(256) void k_js(const float* __restrict__ jreg,
                                            const float* __restrict__ vtmpl,
                                            const float* __restrict__ sdirs,
                                            float* __restrict__ ws) {
    const int chunk = blockIdx.x, jg = blockIdx.y, g = blockIdx.z;
    const int tid = threadIdx.x;
    float acc[4][33];
#pragma unroll
    for (int a = 0; a < 4; ++a)
#pragma unroll
        for (int o = 0; o < 33; ++o) acc[a][o] = 0.f;

    const int v0 = chunk * VCHUNK;
    const int v1 = (v0 + VCHUNK < V) ? v0 + VCHUNK : V;
    const float* jr0 = jreg + (size_t)g * NJ * V;
    const float* sd  = sdirs + (size_t)g * V * 30;
    const float* tm  = vtmpl + (size_t)g * V * 3;

    for (int v = v0 + tid; v < v1; v += 256) {
        float jv[4];
#pragma unroll
        for (int a = 0; a < 4; ++a) jv[a] = jr0[(size_t)(jg*4 + a) * V + v];
        float b[33];
        const float* sdv = sd + (size_t)v * 30;
#pragma unroll
        for (int o = 0; o < 30; o += 2) {
            float2 q = *(const float2*)(sdv + o);
            b[o] = q.x; b[o+1] = q.y;
        }
        b[30] = tm[(size_t)v*3 + 0];
        b[31] = tm[(size_t)v*3 + 1];
        b[32] = tm[(size_t)v*3 + 2];
#pragma unroll
        for (int a = 0; a < 4; ++a)
#pragma unroll
            for (int o = 0; o < 33; ++o) acc[a][o] += jv[a] * b[o];
    }

#pragma unroll
    for (int a = 0; a < 4; ++a)
#pragma unroll
        for (int o = 0; o < 33; ++o) {
            float x = acc[a][o];
#pragma unroll
            for (int s = 32; s >= 1; s >>= 1) x += __shfl_xor(x, s, 64);
            acc[a][o] = x;
        }

    __shared__ float red[4][132];
    const int wvi = tid >> 6, ln = tid & 63;
    if (ln == 0) {
#pragma unroll
        for (int a = 0; a < 4; ++a)
#pragma unroll
            for (int o = 0; o < 33; ++o) red[wvi][a*33 + o] = acc[a][o];
    }
    __syncthreads();
    if (tid < 132) {
        float s = red[0][tid] + red[1][tid] + red[2][tid] + red[3][tid];
        int a = tid / 33, o = tid % 33;
        int j = jg * 4 + a;
        ws[(size_t)((g*NJ + j)*33 + o) * NCHUNK + chunk] = s;
    }
}

// ---------------- Kernel B: joint math, once ----------------
// blocks 0..31: per-slot joint pipeline; blocks 32..39: to_keep lower-bound table
__global__ __launch_bounds__(256) void k_joint(const float* __restrict__ pose,
                                               const float* __restrict__ betas,
                                               const int*   __restrict__ to_keep,
                                               float* __restrict__ ws) {
    const int bid = (int)blockIdx.x;
    const int t = threadIdx.x;
    int* wsI = (int*)ws;
    unsigned* wsU = (unsigned*)ws;

    if (bid >= 32) {   // kb table
        int idx = (bid - 32) * 256 + t;
        if (idx <= NT2) {
            int target = idx * 16;
            int lo = 0, hi = KK;
            while (lo < hi) { int m = (lo + hi) >> 1; if (to_keep[m] < target) lo = m + 1; else hi = m; }
            wsI[WS_KB + idx] = lo;
        }
        return;
    }

    __shared__ float gflag[32];
    __shared__ int   permJ[33];
    __shared__ float jsJ[792];     // [24][33] for this block's gender
    __shared__ float Jloc[96];     // [24][4] padded
    __shared__ float AJ[288];      // [24][12]
    __shared__ float GS[288];      // [24][12] post-corr results

    if (t < 32) gflag[t] = betas[t*11 + 10];
    __syncthreads();
    if (t < 32) {
        bool male = gflag[t] > 0.5f;
        unsigned gm = (unsigned)__ballot(male);
        int cnt0 = 32 - __popc(gm);
        unsigned below = (1u << t) - 1u;
        int slot = male ? (cnt0 + __popc(gm & below)) : __popc((~gm) & below);
        permJ[slot] = t;
        if (t == 0) permJ[32] = cnt0;
    }
    __syncthreads();

    const int slot = bid;
    const int b = permJ[slot];
    const int gi = (gflag[b] > 0.5f) ? 1 : 0;

    if (bid == 0) {
        if (t < 32) wsI[WS_PERM + t] = permJ[t];
        if (t == 0) wsI[WS_CNT] = permJ[32];
    }

    for (int o = t; o < 792; o += 256) {
        const float* p = ws + WS_JS + (size_t)(gi*792 + o) * NCHUNK;
        float s = 0.f;
#pragma unroll
        for (int c = 0; c < NCHUNK; ++c) s += p[c];
        jsJ[o] = s;
    }
    __syncthreads();

    if (t < 72) {
        int j = t / 3, c = t - 3*j;
        const float* jsb = jsJ + j*33;
        float s = jsb[30 + c];
#pragma unroll
        for (int q = 0; q < 10; ++q) s += jsb[c*10 + q] * betas[b*11 + q];
        Jloc[j*4 + c] = s;
    }
    __syncthreads();

    if (t < 24) {
        const float* pp = pose + (size_t)(b*24 + t) * 3;
        float rx = pp[0], ry = pp[1], rz = pp[2];
        float th = fmaxf(sqrtf(rx*rx + ry*ry + rz*rz), 1.1920929e-07f);
        float inv = 1.0f / th;
        float ux = rx*inv, uy = ry*inv, uz = rz*inv;
        float st = sinf(th), ct = cosf(th), oc = 1.0f - ct;
        float* A = AJ + t*12;
        A[0] = ct + oc*ux*ux;    A[1] = oc*ux*uy - st*uz; A[2]  = oc*ux*uz + st*uy;
        A[4] = oc*ux*uy + st*uz; A[5] = ct + oc*uy*uy;    A[6]  = oc*uy*uz - st*ux;
        A[8] = oc*ux*uz - st*uy; A[9] = oc*uy*uz + st*ux; A[10] = ct + oc*uz*uz;
        int par = d_par[t];
#pragma unroll
        for (int r = 0; r < 3; ++r)
            A[r*4 + 3] = Jloc[t*4 + r] - (t > 0 ? Jloc[par*4 + r] : 0.f);
    }
    __syncthreads();

    // A pack: k 0..206 lrot bf16; k 208..217 beta bf16; rest 0
    if (t < 116) {
        float f[2];
#pragma unroll
        for (int h = 0; h < 2; ++h) {
            int k = 2*t + h;
            float val = 0.f;
            if (k < 207) {
                int j = k / 9 + 1, rc = k - 9*(j-1);
                int r = rc / 3, c = rc - 3*r;
                val = AJ[j*12 + r*4 + c] - (r == c ? 1.f : 0.f);
            } else if (k >= 208 && k < 218) {
                val = betas[b*11 + (k - 208)];
            }
            f[h] = val;
        }
        wsU[WS_LA + slot*116 + t] = pk2(f[0], f[1]);
    }

    // kinematic chain: 12 lanes hold G[r][c] per j in registers, shfl for G_par rows
    if (t < 12) {
        constexpr int kPar[24] = {0,0,0,0,1,2,3,4,5,6,7,8,9,9,9,12,13,14,16,17,18,19,20,21};
        const int r = t >> 2, c = t & 3;
        float Greg[24];
        Greg[0] = AJ[t];
#pragma unroll
        for (int j = 1; j < 24; ++j) {
            const int par = kPar[j];
            float a0 = AJ[j*12 + 0 + c];
            float a1 = AJ[j*12 + 4 + c];
            float a2 = AJ[j*12 + 8 + c];
            float g0 = __shfl(Greg[par], r*4 + 0, 64);
            float g1 = __shfl(Greg[par], r*4 + 1, 64);
            float g2 = __shfl(Greg[par], r*4 + 2, 64);
            float g3 = __shfl(Greg[par], r*4 + 3, 64);
            Greg[j] = g0*a0 + g1*a1 + g2*a2 + (c == 3 ? g3 : 0.f);
        }
#pragma unroll
        for (int j = 0; j < 24; ++j) {
            float t0 = __shfl(Greg[j], r*4 + 0, 64);
            float t1 = __shfl(Greg[j], r*4 + 1, 64);
            float t2 = __shfl(Greg[j], r*4 + 2, 64);
            float corr = t0*Jloc[j*4 + 0] + t1*Jloc[j*4 + 1] + t2*Jloc[j*4 + 2];
            if (c == 3) Greg[j] -= corr;
            GS[j*12 + t] = Greg[j];
        }
    }
    __syncthreads();

    // res -> bf16 B-fragments (exactly 256 entries per slot)
    {
        int kg = t >> 6, rem = t & 63, n = rem >> 2, wq = rem & 3;
        int j0 = kg*8 + 2*wq;
        float f0 = (j0 < 24 && n < 12) ? GS[j0*12 + n] : 0.f;
        float f1 = (j0 + 1 < 24 && n < 12) ? GS[(j0+1)*12 + n] : 0.f;
        wsU[WS_RB + slot*256 + t] = pk2(f0, f1);
    }
    // root = results[0] @ (J[0],1)
    if (t < 3) {
        float s = GS[t*4 + 3];
#pragma unroll
        for (int q = 0; q < 3; ++q) s += GS[t*4 + q] * Jloc[q];
        ws[WS_ROOT + slot*3 + t] = s;
    }
}

// ---------------- Kernel C: persistent per-item loop ----------------
// waves_per_eu(4,4): LDS caps at 1 block/CU (16 waves = 4/SIMD); explicit
// max=4 licenses the 128-VGPR budget so the hoisted fragments stay in regs.
__global__ __launch_bounds__(1024)
__attribute__((amdgpu_waves_per_eu(4, 4)))
void k_pose(const float* __restrict__ posedirs,
            const float* __restrict__ sdirs,
            const float* __restrict__ vtmpl,
            const float* __restrict__ wall,
            const int*   __restrict__ to_keep,
            const float* __restrict__ ws,
            float* __restrict__ out) {
    extern __shared__ float L[];
    unsigned* Lu = (unsigned*)L;
    int* Li = (int*)L;
    const unsigned* wsU = (const unsigned*)ws;
    const int* wsI = (const int*)ws;
    const int t = threadIdx.x;
    const int l = t & 63, wv = t >> 6;        // 16 waves
    const int lm = l & 15, lg = l >> 4;
    const int bid = (int)blockIdx.x;

    // ---- item-invariant staging maps ----
    int pdoff[5], pdladr[5];
    bool pdok[5], pdq3[5];
#pragma unroll
    for (int n = 0; n < 5; ++n) {
        int e = t + 1024*n;
        bool ok = e < 4992;
        pdok[n] = ok;
        int e2 = ok ? e : 0;
        int row = e2 / 52, k4 = (e2 - 52*row) * 4;
        int g = row / 48, rr = row - 48*g;
        pdoff[n] = g*(V*621) + rr*207 + k4;
        int kw = k4 >> 1;                                    // bf16-pair word index
        pdladr[n] = LPD + row*128 + (kw ^ ((row & 7) << 2)); // swizzled
        pdq3[n] = (k4 == 204);
    }
    int sdoff = 0, sdladr = 0;
    if (t < 480) {
        int w = 2*t;                    // even -> pair stays within a row (10 f32/row)
        int g = w / 480, w2 = w - 480*g;
        int row = w2 / 10, j = (w2 - 10*row) >> 1;
        int rowg = g*48 + row;
        sdoff = g*(V*30) + w2;
        sdladr = LPD + rowg*128 + ((104 + j) ^ ((rowg & 7) << 2));
    }
    int tmoff = 0;
    if (t < 48)  { int w = 2*t; int g = w/48;  tmoff = g*(V*3) + (w - 48*g); }
    int woff = 0, wladr = 0;
    if (t < 384) {
        int g = t/192, i = t - 192*g;
        int v = i/12, wi = i - 12*v;
        int kgrp = wi >> 2, wq = wi & 3;
        int j0 = kgrp*8 + 2*wq;
        woff = g*(V*24) + v*24 + j0;
        wladr = LWA + g*256 + kgrp*64 + v*4 + wq;
    }

    float4 pdreg[5]; float2 sdreg = {0,0}, tmreg = {0,0}, wreg = {0,0};

    const int PDLIM = 2*V*621 - 4;
    const int SDLIM = 2*V*30 - 2;
    const int TMLIM = 2*V*3 - 2;
    const int WLIM  = 2*V*24 - 2;

    auto issue_loads = [&](int itm) {
        const int vb = itm * 16;
#pragma unroll
        for (int n = 0; n < 5; ++n) {
            int a = vb*621 + pdoff[n];
            if (a > PDLIM) a = PDLIM;
            f32x4a q = *(const f32x4a*)(posedirs + a);   // one dwordx4, lane-contiguous
            pdreg[n].x = q.x;
            pdreg[n].y = q.y;
            pdreg[n].z = q.z;
            pdreg[n].w = pdq3[n] ? 0.f : q.w;
        }
        if (t < 480) { int a = vb*30 + sdoff; if (a > SDLIM) a = SDLIM; sdreg = *(const float2*)(sdirs + a); }
        if (t < 48)  { int a = vb*3  + tmoff; if (a > TMLIM) a = TMLIM; tmreg = *(const float2*)(vtmpl + a); }
        if (t < 384) { int a = vb*24 + woff;  if (a > WLIM)  a = WLIM;  wreg  = *(const float2*)(wall  + a); }
    };

    auto write_stage = [&]() {
#pragma unroll
        for (int n = 0; n < 5; ++n)
            if (pdok[n]) {
                uint2 v;
                v.x = pk2(pdreg[n].x, pdreg[n].y);
                v.y = pk2(pdreg[n].z, pdreg[n].w);
                *(uint2*)&Lu[pdladr[n]] = v;
            }
        if (t < 480) Lu[sdladr] = pk2(sdreg.x, sdreg.y);
        if (t < 48)  { L[LTM2 + 2*t] = tmreg.x; L[LTM2 + 2*t + 1] = tmreg.y; }
        if (t < 384) Lu[wladr] = pk2(wreg.x, wreg.y);
    };

    issue_loads(bid);

    // ================= stage precomputed joint data from workspace =================
    {
        for (int i = t; i < 928; i += 1024)
            *(uint4*)&Lu[LA + 4*i] = *(const uint4*)&wsU[WS_LA + 4*i];
        for (int i = t; i < 2048; i += 1024)
            *(uint4*)&Lu[LRB + 4*i] = *(const uint4*)&wsU[WS_RB + 4*i];
        if (t < 96)  L[LROOT2 + t] = ws[WS_ROOT + t];
        if (t < 32)  Li[LPERM2 + t] = wsI[WS_PERM + t];
        if (t == 0)  Li[LCNT2] = wsI[WS_CNT];
        if (t < 8) {
            int idx = bid + 256*t;
            int kst = KK, ken = KK;
            if (idx < NT2) { kst = wsI[WS_KB + idx]; ken = wsI[WS_KB + idx + 1]; }
            Li[LKB + t] = kst; Li[LKB + 8 + t] = ken;
        }
        if (t < 128) Lu[LWA + (t >> 6)*256 + 192 + (t & 63)] = 0;   // kgrp=3 zero pad
        // zero pd pad: logical words kw 109..111 per row (read range covers kw<112)
        if (t < 288) {
            int row = t / 3, j2 = 109 + (t - 3*(t/3));
            Lu[LPD + row*128 + (j2 ^ ((row & 7) << 2))] = 0;
        }
        __syncthreads();
    }

    const int cnt0v = Li[LCNT2];
    const int cnt1 = 32 - cnt0v;
    const int m0 = (cnt0v + 15) >> 4, m1 = (cnt1 + 15) >> 4;
    const int ntA = 3*m0, ntasks = 3*(m0 + m1);

    int rb0 = -1, nt0 = 0, sb0 = 0, ct0 = 0, gi0 = 0;
    if (wv < ntasks) {
        int gi = (wv >= ntA) ? 1 : 0; int tt = gi ? wv - ntA : wv;
        int mt = tt / 3; nt0 = tt - 3*mt;
        sb0 = gi ? cnt0v : 0; ct0 = gi ? cnt1 : cnt0v;
        rb0 = sb0 + mt*16; gi0 = gi;
    }

    // ---- hoist item-invariant MFMA fragments into registers (needs >64 VGPR cap) ----
    uint4 afrag[7];                       // lrot+beta A-fragments (wave task fixed)
#pragma unroll
    for (int kk = 0; kk < 7; ++kk) afrag[kk] = uint4{0,0,0,0};
    if (rb0 >= 0) {
        const unsigned* ap = Lu + LA + (rb0 + lm)*116 + (lg << 2);
#pragma unroll
        for (int kk = 0; kk < 7; ++kk) afrag[kk] = *(const uint4*)(ap + kk*16);
    }
    uint4 bfragT[2];                      // res B-fragments (wave slots fixed)
#pragma unroll
    for (int q = 0; q < 2; ++q) {
        int s = wv*2 + q;
        bfragT[q] = *(const uint4*)(Lu + LRB + s*256 + lg*64 + lm*4);
    }

    const int bs = t >> 5, kl0 = t & 31;
    const int borig = Li[LPERM2 + bs];
    const float rt0 = L[LROOT2 + bs*3 + 0];
    const float rt1 = L[LROOT2 + bs*3 + 1];
    const float rt2 = L[LROOT2 + bs*3 + 2];
    const int s4 = (lm & 7) << 2;   // B-read swizzle (row&7 == lm&7)

    write_stage();
    __syncthreads();

    int li = 0;
    for (int item = bid; item < NT2; item += 256, ++li) {
        const bool more = (item + 256 < NT2);
        if (more) issue_loads(item + 256);   // stays in flight across BOTH in-loop barriers

        // ---- pose+shape MFMA: D[slot][n=3v+c] = lrot.pd + beta.sd (A in regs) ----
        f32x4 acc0 = {0,0,0,0};
        if (rb0 >= 0) {
            const unsigned* bp = Lu + LPD + (gi0*48 + nt0*16 + lm)*128;
#pragma unroll
            for (int kk = 0; kk < 7; ++kk) {
                S8U4 a; a.u4 = afrag[kk];
                S8U4 bb; bb.u4 = *(const uint4*)(bp + ((kk*16 + (lg << 2)) ^ s4));
                acc0 = __builtin_amdgcn_mfma_f32_16x16x32_bf16(a.s, bb.s, acc0, 0, 0, 0);
            }
        }

        // ---- vposed = acc + template ----
        if (rb0 >= 0) {
            int n = nt0*16 + lm;
            int vd = n / 3, cd = n - 3*vd;
            float tmv = L[LTM2 + gi0*48 + n];
#pragma unroll
            for (int r = 0; r < 4; ++r) {
                int slot = rb0 + (lg << 2) + r;
                if ((unsigned)(slot - sb0) < (unsigned)ct0)
                    L[LVP + slot*68 + vd*4 + cd] = acc0[r] + tmv;
            }
        }

        // ---- T MFMA: T[slot][v][pq] = sum_j w[v][j] res[slot][j][pq] (B in regs) ----
#pragma unroll
        for (int q = 0; q < 2; ++q) {
            int s = wv*2 + q;
            int gsl = (s >= cnt0v) ? 1 : 0;
            S8U4 a; a.u4 = *(const uint4*)(Lu + LWA + gsl*256 + lg*64 + lm*4);
            S8U4 b; b.u4 = bfragT[q];
            f32x4 acT = {0,0,0,0};
            acT = __builtin_amdgcn_mfma_f32_16x16x32_bf16(a.s, b.s, acT, 0, 0, 0);
#pragma unroll
            for (int r = 0; r < 4; ++r)
                L[LT + s*320 + (lg*4 + r)*20 + lm] = acT[r];
        }
        BAR_LGKM();   // LVP/LT visible; LPD/LWA/LTM2 reads drained; prefetch vmcnt NOT drained

        // ---- epilogue (reads LVP/LT) overlapped with next-item staging (writes LPD/LWA/LTM2) ----
        const int kst = Li[LKB + li], ken = Li[LKB + 8 + li];
        const int v0w = item * 16;
        for (int k = kst + kl0; k < ken; k += 32) {
            const int vr = to_keep[k] - v0w;
            const float4 vp = *(const float4*)&L[LVP + bs*68 + vr*4];
            const float4 t0 = *(const float4*)&L[LT + bs*320 + vr*20];
            const float4 t1 = *(const float4*)&L[LT + bs*320 + vr*20 + 4];
            const float4 t2 = *(const float4*)&L[LT + bs*320 + vr*20 + 8];
            const size_t ob = ((size_t)borig*KK + (size_t)k)*3;
            out[ob]   = t0.x*vp.x + t0.y*vp.y + t0.z*vp.z + t0.w - rt0;
            out[ob+1] = t1.x*vp.x + t1.y*vp.y + t1.z*vp.z + t1.w - rt1;
            out[ob+2] = t2.x*vp.x + t2.y*vp.y + t2.z*vp.z + t2.w - rt2;
        }
        if (more) write_stage();   // compiler inserts vmcnt wait for pdreg HERE (max slack)
        BAR_LGKM();   // staged LDS visible for next iter; epilogue LVP/LT reads drained
    }
}

extern "C" void kernel_launch(void* const* d_in, const int* in_sizes, int n_in,
                              void* d_out, int out_size, void* d_ws, size_t ws_size,
                              hipStream_t stream) {
    const float* pose     = (const float*)d_in[0];
    const float* betas    = (const float*)d_in[1];
    const float* jreg     = (const float*)d_in[2];
    const float* vtmpl    = (const float*)d_in[3];
    const float* sdirs    = (const float*)d_in[4];
    const float* posedirs = (const float*)d_in[5];
    const float* wall     = (const float*)d_in[6];
    const int*   to_keep  = (const int*)d_in[7];
    float* ws  = (float*)d_ws;
    float* out = (float*)d_out;

    hipFuncSetAttribute((const void*)k_pose,
                        hipFuncAttributeMaxDynamicSharedMemorySize,
                        LDSW * 4);

    hipLaunchKernelGGL(k_js,    dim3(NCHUNK, 6, 2), dim3(256), 0, stream, jreg, vtmpl, sdirs, ws);
    hipLaunchKernelGGL(k_joint, dim3(40),           dim3(256), 0, stream, pose, betas, to_keep, ws);
    hipLaunchKernelGGL(k_pose,  dim3(256),          dim3(1024), LDSW * 4, stream,
                       posedirs, sdirs, vtmpl, wall, to_keep, ws, out);
}

// Round 13
// 67.215 us; speedup vs baseline: 1.5274x; 1.5274x over previous
//
#include <hip/hip_runtime.h>
#include <hip/hip_bf16.h>
#include <cstdint>
#include <cstddef>

#define V      27578
#define NJ     24
#define KK     24000
#define NT2    1724          /* ceil(V/16) */
#define NCHUNK 21            /* 21*12 = 252 blocks: single balanced generation on 256 CUs */
#define VCHUNK 1314

// ---------------- k_pose LDS layout (f32/u32 word offsets) ----------------
#define LPD    0             // u32 [96 rows=(g*48+3v+c)][128] bf16-pair words, XOR-swizzled; kw 104..108 = shapedirs
#define LA     12288         // u32 [32 slots][116] lrot+beta bf16 pairs (k 0..206 lrot, 208..217 beta)
#define LRB    16000         // u32 [32][4 kgrp][16 n][4] res bf16 B-fragments
#define LVP    24192         // f32 [32 slots][68] vposed (vd*4+cd)
#define LT     26368         // f32 [32 slots][16 v][20] T matrices
#define LWA    36608         // u32 [2 g][4 kgrp][16 v][4] weights bf16 A-fragments
#define LTM2   37120         // f32 [96] template tile (g*48+n)
#define LROOT2 37216         // f32 [32 slots][3]
#define LPERM2 37312         // int [32]
#define LCNT2  37344         // int
#define LKB    37348         // int [2][8]
#define LDSW   37364         // 149,456 bytes

// ---------------- workspace layout (word offsets) ----------------
#define WS_JS   0            // f32 [2][24][33][21]  (k_js partials)
#define WS_LA   33264        // u32 [32][116]
#define WS_RB   36976        // u32 [32][256]
#define WS_ROOT 45168        // f32 [32][3]
#define WS_PERM 45264        // int [32]
#define WS_CNT  45296        // int
#define WS_KB   45300        // int [1725]  kb[i] = lower_bound(to_keep, 16*i)

typedef short short8 __attribute__((ext_vector_type(8)));
typedef float f32x4 __attribute__((ext_vector_type(4)));
typedef float f32x4a __attribute__((ext_vector_type(4), aligned(4)));   // dword-aligned vector load

union S8U4 { unsigned u[4]; uint4 u4; short8 s; };

__device__ __forceinline__ unsigned pk2(float a, float b) {
    __hip_bfloat162 h = __float22bfloat162_rn(float2{a, b});
    union { __hip_bfloat162 h; unsigned u; } cv; cv.h = h;
    return cv.u;
}

// LDS-only barrier: drains ds ops (lgkmcnt) but leaves the global prefetch
// (vmcnt) in flight — its wait moves to write_stage's data-flow use.
#define BAR_LGKM() do { \
    asm volatile("s_waitcnt lgkmcnt(0)\n\ts_barrier" ::: "memory"); \
    __builtin_amdgcn_sched_barrier(0); \
} while (0)

__constant__ int d_par[24] = {0,0,0,0,1,2,3,4,5,6,7,8,9,9,9,12,13,14,16,17,18,19,20,21};

// ---------------- Kernel A: JS/Jt partials over V-chunks ----------------
__global__ __launch_bounds__(256) void k_js(const float* __restrict__ jreg,
                                            const float* __restrict__ vtmpl,
                                            const float* __restrict__ sdirs,
                                            float* __restrict__ ws) {
    const int chunk = blockIdx.x, jg = blockIdx.y, g = blockIdx.z;
    const int tid = threadIdx.x;
    float acc[4][33];
#pragma unroll
    for (int a = 0; a < 4; ++a)
#pragma unroll
        for (int o = 0; o < 33; ++o) acc[a][o] = 0.f;

    const int v0 = chunk * VCHUNK;
    const int v1 = (v0 + VCHUNK < V) ? v0 + VCHUNK : V;
    const float* jr0 = jreg + (size_t)g * NJ * V;
    const float* sd  = sdirs + (size_t)g * V * 30;
    const float* tm  = vtmpl + (size_t)g * V * 3;

    for (int v = v0 + tid; v < v1; v += 256) {
        float jv[4];
#pragma unroll
        for (int a = 0; a < 4; ++a) jv[a] = jr0[(size_t)(jg*4 + a) * V + v];
        float b[33];
        const float* sdv = sd + (size_t)v * 30;
#pragma unroll
        for (int o = 0; o < 30; o += 2) {
            float2 q = *(const float2*)(sdv + o);
            b[o] = q.x; b[o+1] = q.y;
        }
        b[30] = tm[(size_t)v*3 + 0];
        b[31] = tm[(size_t)v*3 + 1];
        b[32] = tm[(size_t)v*3 + 2];
#pragma unroll
        for (int a = 0; a < 4; ++a)
#pragma unroll
            for (int o = 0; o < 33; ++o) acc[a][o] += jv[a] * b[o];
    }

#pragma unroll
    for (int a = 0; a < 4; ++a)
#pragma unroll
        for (int o = 0; o < 33; ++o) {
            float x = acc[a][o];
#pragma unroll
            for (int s = 32; s >= 1; s >>= 1) x += __shfl_xor(x, s, 64);
            acc[a][o] = x;
        }

    __shared__ float red[4][132];
    const int wvi = tid >> 6, ln = tid & 63;
    if (ln == 0) {
#pragma unroll
        for (int a = 0; a < 4; ++a)
#pragma unroll
            for (int o = 0; o < 33; ++o) red[wvi][a*33 + o] = acc[a][o];
    }
    __syncthreads();
    if (tid < 132) {
        float s = red[0][tid] + red[1][tid] + red[2][tid] + red[3][tid];
        int a = tid / 33, o = tid % 33;
        int j = jg * 4 + a;
        ws[(size_t)((g*NJ + j)*33 + o) * NCHUNK + chunk] = s;
    }
}

// ---------------- Kernel B: joint math, once ----------------
// blocks 0..31: per-slot joint pipeline; blocks 32..39: to_keep lower-bound table
__global__ __launch_bounds__(256) void k_joint(const float* __restrict__ pose,
                                               const float* __restrict__ betas,
                                               const int*   __restrict__ to_keep,
                                               float* __restrict__ ws) {
    const int bid = (int)blockIdx.x;
    const int t = threadIdx.x;
    int* wsI = (int*)ws;
    unsigned* wsU = (unsigned*)ws;

    if (bid >= 32) {   // kb table
        int idx = (bid - 32) * 256 + t;
        if (idx <= NT2) {
            int target = idx * 16;
            int lo = 0, hi = KK;
            while (lo < hi) { int m = (lo + hi) >> 1; if (to_keep[m] < target) lo = m + 1; else hi = m; }
            wsI[WS_KB + idx] = lo;
        }
        return;
    }

    __shared__ float gflag[32];
    __shared__ int   permJ[33];
    __shared__ float jsJ[792];     // [24][33] for this block's gender
    __shared__ float Jloc[96];     // [24][4] padded
    __shared__ float AJ[288];      // [24][12]
    __shared__ float GS[288];      // [24][12] post-corr results

    if (t < 32) gflag[t] = betas[t*11 + 10];
    __syncthreads();
    if (t < 32) {
        bool male = gflag[t] > 0.5f;
        unsigned gm = (unsigned)__ballot(male);
        int cnt0 = 32 - __popc(gm);
        unsigned below = (1u << t) - 1u;
        int slot = male ? (cnt0 + __popc(gm & below)) : __popc((~gm) & below);
        permJ[slot] = t;
        if (t == 0) permJ[32] = cnt0;
    }
    __syncthreads();

    const int slot = bid;
    const int b = permJ[slot];
    const int gi = (gflag[b] > 0.5f) ? 1 : 0;

    if (bid == 0) {
        if (t < 32) wsI[WS_PERM + t] = permJ[t];
        if (t == 0) wsI[WS_CNT] = permJ[32];
    }

    for (int o = t; o < 792; o += 256) {
        const float* p = ws + WS_JS + (size_t)(gi*792 + o) * NCHUNK;
        float s = 0.f;
#pragma unroll
        for (int c = 0; c < NCHUNK; ++c) s += p[c];
        jsJ[o] = s;
    }
    __syncthreads();

    if (t < 72) {
        int j = t / 3, c = t - 3*j;
        const float* jsb = jsJ + j*33;
        float s = jsb[30 + c];
#pragma unroll
        for (int q = 0; q < 10; ++q) s += jsb[c*10 + q] * betas[b*11 + q];
        Jloc[j*4 + c] = s;
    }
    __syncthreads();

    if (t < 24) {
        const float* pp = pose + (size_t)(b*24 + t) * 3;
        float rx = pp[0], ry = pp[1], rz = pp[2];
        float th = fmaxf(sqrtf(rx*rx + ry*ry + rz*rz), 1.1920929e-07f);
        float inv = 1.0f / th;
        float ux = rx*inv, uy = ry*inv, uz = rz*inv;
        float st = sinf(th), ct = cosf(th), oc = 1.0f - ct;
        float* A = AJ + t*12;
        A[0] = ct + oc*ux*ux;    A[1] = oc*ux*uy - st*uz; A[2]  = oc*ux*uz + st*uy;
        A[4] = oc*ux*uy + st*uz; A[5] = ct + oc*uy*uy;    A[6]  = oc*uy*uz - st*ux;
        A[8] = oc*ux*uz - st*uy; A[9] = oc*uy*uz + st*ux; A[10] = ct + oc*uz*uz;
        int par = d_par[t];
#pragma unroll
        for (int r = 0; r < 3; ++r)
            A[r*4 + 3] = Jloc[t*4 + r] - (t > 0 ? Jloc[par*4 + r] : 0.f);
    }
    __syncthreads();

    // A pack: k 0..206 lrot bf16; k 208..217 beta bf16; rest 0
    if (t < 116) {
        float f[2];
#pragma unroll
        for (int h = 0; h < 2; ++h) {
            int k = 2*t + h;
            float val = 0.f;
            if (k < 207) {
                int j = k / 9 + 1, rc = k - 9*(j-1);
                int r = rc / 3, c = rc - 3*r;
                val = AJ[j*12 + r*4 + c] - (r == c ? 1.f : 0.f);
            } else if (k >= 208 && k < 218) {
                val = betas[b*11 + (k - 208)];
            }
            f[h] = val;
        }
        wsU[WS_LA + slot*116 + t] = pk2(f[0], f[1]);
    }

    // kinematic chain: 12 lanes hold G[r][c] per j in registers, shfl for G_par rows
    if (t < 12) {
        constexpr int kPar[24] = {0,0,0,0,1,2,3,4,5,6,7,8,9,9,9,12,13,14,16,17,18,19,20,21};
        const int r = t >> 2, c = t & 3;
        float Greg[24];
        Greg[0] = AJ[t];
#pragma unroll
        for (int j = 1; j < 24; ++j) {
            const int par = kPar[j];
            float a0 = AJ[j*12 + 0 + c];
            float a1 = AJ[j*12 + 4 + c];
            float a2 = AJ[j*12 + 8 + c];
            float g0 = __shfl(Greg[par], r*4 + 0, 64);
            float g1 = __shfl(Greg[par], r*4 + 1, 64);
            float g2 = __shfl(Greg[par], r*4 + 2, 64);
            float g3 = __shfl(Greg[par], r*4 + 3, 64);
            Greg[j] = g0*a0 + g1*a1 + g2*a2 + (c == 3 ? g3 : 0.f);
        }
#pragma unroll
        for (int j = 0; j < 24; ++j) {
            float t0 = __shfl(Greg[j], r*4 + 0, 64);
            float t1 = __shfl(Greg[j], r*4 + 1, 64);
            float t2 = __shfl(Greg[j], r*4 + 2, 64);
            float corr = t0*Jloc[j*4 + 0] + t1*Jloc[j*4 + 1] + t2*Jloc[j*4 + 2];
            if (c == 3) Greg[j] -= corr;
            GS[j*12 + t] = Greg[j];
        }
    }
    __syncthreads();

    // res -> bf16 B-fragments (exactly 256 entries per slot)
    {
        int kg = t >> 6, rem = t & 63, n = rem >> 2, wq = rem & 3;
        int j0 = kg*8 + 2*wq;
        float f0 = (j0 < 24 && n < 12) ? GS[j0*12 + n] : 0.f;
        float f1 = (j0 + 1 < 24 && n < 12) ? GS[(j0+1)*12 + n] : 0.f;
        wsU[WS_RB + slot*256 + t] = pk2(f0, f1);
    }
    // root = results[0] @ (J[0],1)
    if (t < 3) {
        float s = GS[t*4 + 3];
#pragma unroll
        for (int q = 0; q < 3; ++q) s += GS[t*4 + q] * Jloc[q];
        ws[WS_ROOT + slot*3 + t] = s;
    }
}

// ---------------- Kernel C: persistent per-item loop ----------------
__global__ __launch_bounds__(1024)
__attribute__((amdgpu_waves_per_eu(4, 4)))
void k_pose(const float* __restrict__ posedirs,
            const float* __restrict__ sdirs,
            const float* __restrict__ vtmpl,
            const float* __restrict__ wall,
            const int*   __restrict__ to_keep,
            const float* __restrict__ ws,
            float* __restrict__ out) {
    extern __shared__ float L[];
    unsigned* Lu = (unsigned*)L;
    int* Li = (int*)L;
    const unsigned* wsU = (const unsigned*)ws;
    const int* wsI = (const int*)ws;
    const int t = threadIdx.x;
    const int l = t & 63, wv = t >> 6;        // 16 waves
    const int lm = l & 15, lg = l >> 4;
    const int bid = (int)blockIdx.x;

    // ---- item-invariant staging maps ----
    int pdoff[5], pdladr[5];
    bool pdok[5], pdq3[5];
#pragma unroll
    for (int n = 0; n < 5; ++n) {
        int e = t + 1024*n;
        bool ok = e < 4992;
        pdok[n] = ok;
        int e2 = ok ? e : 0;
        int row = e2 / 52, k4 = (e2 - 52*row) * 4;
        int g = row / 48, rr = row - 48*g;
        pdoff[n] = g*(V*621) + rr*207 + k4;
        int kw = k4 >> 1;                                    // bf16-pair word index
        pdladr[n] = LPD + row*128 + (kw ^ ((row & 7) << 2)); // swizzled
        pdq3[n] = (k4 == 204);
    }
    int sdoff = 0, sdladr = 0;
    if (t < 480) {
        int w = 2*t;                    // even -> pair stays within a row (10 f32/row)
        int g = w / 480, w2 = w - 480*g;
        int row = w2 / 10, j = (w2 - 10*row) >> 1;
        int rowg = g*48 + row;
        sdoff = g*(V*30) + w2;
        sdladr = LPD + rowg*128 + ((104 + j) ^ ((rowg & 7) << 2));
    }
    int tmoff = 0;
    if (t < 48)  { int w = 2*t; int g = w/48;  tmoff = g*(V*3) + (w - 48*g); }
    int woff = 0, wladr = 0;
    if (t < 384) {
        int g = t/192, i = t - 192*g;
        int v = i/12, wi = i - 12*v;
        int kgrp = wi >> 2, wq = wi & 3;
        int j0 = kgrp*8 + 2*wq;
        woff = g*(V*24) + v*24 + j0;
        wladr = LWA + g*256 + kgrp*64 + v*4 + wq;
    }

    float4 pdreg[5]; float2 sdreg = {0,0}, tmreg = {0,0}, wreg = {0,0};

    const int PDLIM = 2*V*621 - 4;
    const int SDLIM = 2*V*30 - 2;
    const int TMLIM = 2*V*3 - 2;
    const int WLIM  = 2*V*24 - 2;

    auto issue_loads = [&](int itm) {
        const int vb = itm * 16;
#pragma unroll
        for (int n = 0; n < 5; ++n) {
            int a = vb*621 + pdoff[n];
            if (a > PDLIM) a = PDLIM;
            f32x4a q = *(const f32x4a*)(posedirs + a);   // one dwordx4, lane-contiguous
            pdreg[n].x = q.x;
            pdreg[n].y = q.y;
            pdreg[n].z = q.z;
            pdreg[n].w = pdq3[n] ? 0.f : q.w;
        }
        if (t < 480) { int a = vb*30 + sdoff; if (a > SDLIM) a = SDLIM; sdreg = *(const float2*)(sdirs + a); }
        if (t < 48)  { int a = vb*3  + tmoff; if (a > TMLIM) a = TMLIM; tmreg = *(const float2*)(vtmpl + a); }
        if (t < 384) { int a = vb*24 + woff;  if (a > WLIM)  a = WLIM;  wreg  = *(const float2*)(wall  + a); }
    };

    auto write_stage = [&]() {
#pragma unroll
        for (int n = 0; n < 5; ++n)
            if (pdok[n]) {
                uint2 v;
                v.x = pk2(pdreg[n].x, pdreg[n].y);
                v.y = pk2(pdreg[n].z, pdreg[n].w);
                *(uint2*)&Lu[pdladr[n]] = v;
            }
        if (t < 480) Lu[sdladr] = pk2(sdreg.x, sdreg.y);
        if (t < 48)  { L[LTM2 + 2*t] = tmreg.x; L[LTM2 + 2*t + 1] = tmreg.y; }
        if (t < 384) Lu[wladr] = pk2(wreg.x, wreg.y);
    };

    issue_loads(bid);

    // ================= stage precomputed joint data from workspace =================
    {
        for (int i = t; i < 928; i += 1024)
            *(uint4*)&Lu[LA + 4*i] = *(const uint4*)&wsU[WS_LA + 4*i];
        for (int i = t; i < 2048; i += 1024)
            *(uint4*)&Lu[LRB + 4*i] = *(const uint4*)&wsU[WS_RB + 4*i];
        if (t < 96)  L[LROOT2 + t] = ws[WS_ROOT + t];
        if (t < 32)  Li[LPERM2 + t] = wsI[WS_PERM + t];
        if (t == 0)  Li[LCNT2] = wsI[WS_CNT];
        if (t < 8) {
            int idx = bid + 256*t;
            int kst = KK, ken = KK;
            if (idx < NT2) { kst = wsI[WS_KB + idx]; ken = wsI[WS_KB + idx + 1]; }
            Li[LKB + t] = kst; Li[LKB + 8 + t] = ken;
        }
        if (t < 128) Lu[LWA + (t >> 6)*256 + 192 + (t & 63)] = 0;   // kgrp=3 zero pad
        // zero pd pad: logical words kw 109..111 per row (read range covers kw<112)
        if (t < 288) {
            int row = t / 3, j2 = 109 + (t - 3*(t/3));
            Lu[LPD + row*128 + (j2 ^ ((row & 7) << 2))] = 0;
        }
        __syncthreads();
    }

    const int cnt0v = Li[LCNT2];
    const int cnt1 = 32 - cnt0v;
    const int m0 = (cnt0v + 15) >> 4, m1 = (cnt1 + 15) >> 4;
    const int ntA = 3*m0, ntasks = 3*(m0 + m1);

    int rb0 = -1, nt0 = 0, sb0 = 0, ct0 = 0, gi0 = 0;
    if (wv < ntasks) {
        int gi = (wv >= ntA) ? 1 : 0; int tt = gi ? wv - ntA : wv;
        int mt = tt / 3; nt0 = tt - 3*mt;
        sb0 = gi ? cnt0v : 0; ct0 = gi ? cnt1 : cnt0v;
        rb0 = sb0 + mt*16; gi0 = gi;
    }

    const int bs = t >> 5, kl0 = t & 31;
    const int borig = Li[LPERM2 + bs];
    const float rt0 = L[LROOT2 + bs*3 + 0];
    const float rt1 = L[LROOT2 + bs*3 + 1];
    const float rt2 = L[LROOT2 + bs*3 + 2];
    const int s4 = (lm & 7) << 2;   // B-read swizzle (row&7 == lm&7)

    write_stage();
    __syncthreads();

    int li = 0;
    for (int item = bid; item < NT2; item += 256, ++li) {
        const bool more = (item + 256 < NT2);
        if (more) issue_loads(item + 256);   // stays in flight across BOTH in-loop barriers

        // ---- pose+shape MFMA: D[slot][n=3v+c] = lrot.pd + beta.sd ----
        f32x4 acc0 = {0,0,0,0};
        if (rb0 >= 0) {
            const unsigned* ap = Lu + LA + (rb0 + lm)*116 + (lg << 2);
            const unsigned* bp = Lu + LPD + (gi0*48 + nt0*16 + lm)*128;
#pragma unroll
            for (int kk = 0; kk < 7; ++kk) {
                S8U4 a; a.u4 = *(const uint4*)(ap + kk*16);
                S8U4 bb; bb.u4 = *(const uint4*)(bp + ((kk*16 + (lg << 2)) ^ s4));
                acc0 = __builtin_amdgcn_mfma_f32_16x16x32_bf16(a.s, bb.s, acc0, 0, 0, 0);
            }
        }

        // ---- vposed = acc + template ----
        if (rb0 >= 0) {
            int n = nt0*16 + lm;
            int vd = n / 3, cd = n - 3*vd;
            float tmv = L[LTM2 + gi0*48 + n];
#pragma unroll
            for (int r = 0; r < 4; ++r) {
                int slot = rb0 + (lg << 2) + r;
                if ((unsigned)(slot - sb0) < (unsigned)ct0)
                    L[LVP + slot*68 + vd*4 + cd] = acc0[r] + tmv;
            }
        }

        // ---- T MFMA: T[slot][v][pq] = sum_j w[v][j] res[slot][j][pq] ----
#pragma unroll
        for (int q = 0; q < 2; ++q) {
            int s = wv*2 + q;
            int gsl = (s >= cnt0v) ? 1 : 0;
            S8U4 a; a.u4 = *(const uint4*)(Lu + LWA + gsl*256 + lg*64 + lm*4);
            S8U4 b; b.u4 = *(const uint4*)(Lu + LRB + s*256 + lg*64 + lm*4);
            f32x4 acT = {0,0,0,0};
            acT = __builtin_amdgcn_mfma_f32_16x16x32_bf16(a.s, b.s, acT, 0, 0, 0);
#pragma unroll
            for (int r = 0; r < 4; ++r)
                L[LT + s*320 + (lg*4 + r)*20 + lm] = acT[r];
        }
        BAR_LGKM();   // LVP/LT visible; LPD/LWA/LTM2 reads drained; prefetch vmcnt NOT drained

        // ---- epilogue (reads LVP/LT) overlapped with next-item staging (writes LPD/LWA/LTM2) ----
        const int kst = Li[LKB + li], ken = Li[LKB + 8 + li];
        const int v0w = item * 16;
        for (int k = kst + kl0; k < ken; k += 32) {
            const int vr = to_keep[k] - v0w;
            const float4 vp = *(const float4*)&L[LVP + bs*68 + vr*4];
            const float4 t0 = *(const float4*)&L[LT + bs*320 + vr*20];
            const float4 t1 = *(const float4*)&L[LT + bs*320 + vr*20 + 4];
            const float4 t2 = *(const float4*)&L[LT + bs*320 + vr*20 + 8];
            const size_t ob = ((size_t)borig*KK + (size_t)k)*3;
            out[ob]   = t0.x*vp.x + t0.y*vp.y + t0.z*vp.z + t0.w - rt0;
            out[ob+1] = t1.x*vp.x + t1.y*vp.y + t1.z*vp.z + t1.w - rt1;
            out[ob+2] = t2.x*vp.x + t2.y*vp.y + t2.z*vp.z + t2.w - rt2;
        }
        if (more) write_stage();   // compiler inserts vmcnt wait for pdreg HERE (max slack)
        BAR_LGKM();   // staged LDS visible for next iter; epilogue LVP/LT reads drained
    }
}

extern "C" void kernel_launch(void* const* d_in, const int* in_sizes, int n_in,
                              void* d_out, int out_size, void* d_ws, size_t ws_size,
                              hipStream_t stream) {
    const float* pose     = (const float*)d_in[0];
    const float* betas    = (const float*)d_in[1];
    const float* jreg     = (const float*)d_in[2];
    const float* vtmpl    = (const float*)d_in[3];
    const float* sdirs    = (const float*)d_in[4];
    const float* posedirs = (const float*)d_in[5];
    const float* wall     = (const float*)d_in[6];
    const int*   to_keep  = (const int*)d_in[7];
    float* ws  = (float*)d_ws;
    float* out = (float*)d_out;

    hipFuncSetAttribute((const void*)k_pose,
                        hipFuncAttributeMaxDynamicSharedMemorySize,
                        LDSW * 4);

    hipLaunchKernelGGL(k_js,    dim3(NCHUNK, 6, 2), dim3(256), 0, stream, jreg, vtmpl, sdirs, ws);
    hipLaunchKernelGGL(k_joint, dim3(40),           dim3(256), 0, stream, pose, betas, to_keep, ws);
    hipLaunchKernelGGL(k_pose,  dim3(256),          dim3(1024), LDSW * 4, stream,
                       posedirs, sdirs, vtmpl, wall, to_keep, ws, out);
}